// Round 1
// baseline (59.398 us; speedup 1.0000x reference)
//
#include <hip/hip_runtime.h>

// PixelEffectModule: 8-bin intensity histogram over 11x11 windows at stride 8,
// pick argmax bin, output that bin's mean RGB, upsampled 8x8.
// Input:  rgb (1,3,2048,2048) fp32, values [0,255)
// Output: (1,3,2048,2048) fp32

#define H 2048
#define W 2048
#define NB 8          // param_num_bins
#define K 11          // param_kernel_size
#define PAD 5         // (K-1)/2
#define PS 8          // param_pixel_size (= conv stride)
#define OH (H / PS)   // 256
#define OW (W / PS)   // 256

__global__ __launch_bounds__(256)
void pixel_effect_kernel(const float* __restrict__ rgb, float* __restrict__ out) {
    int idx = blockIdx.x * blockDim.x + threadIdx.x;
    if (idx >= OH * OW) return;
    int ox = idx & (OW - 1);
    int oy = idx >> 8;

    const float* __restrict__ Rp = rgb;
    const float* __restrict__ Gp = rgb + (size_t)H * W;
    const float* __restrict__ Bp = rgb + 2 * (size_t)H * W;

    float cnt[NB], sr[NB], sg[NB], sb[NB];
#pragma unroll
    for (int i = 0; i < NB; ++i) { cnt[i] = 0.0f; sr[i] = 0.0f; sg[i] = 0.0f; sb[i] = 0.0f; }

    int xs = ox * PS - PAD;
    int ys = oy * PS - PAD;
    int x0 = xs < 0 ? 0 : xs;
    int y0 = ys < 0 ? 0 : ys;
    int x1 = xs + K - 1; if (x1 > W - 1) x1 = W - 1;
    int y1 = ys + K - 1; if (y1 > H - 1) y1 = H - 1;

    for (int y = y0; y <= y1; ++y) {
        int rowoff = y * W;
        for (int x = x0; x <= x1; ++x) {
            float r = Rp[rowoff + x];
            float g = Gp[rowoff + x];
            float b = Bp[rowoff + x];
            // bin = trunc( ((r+g+b)/3) / 256 * 8 )  ; /256*8 == *2^-5 (exact)
            float m = (r + g + b) / 3.0f;
            int bin = (int)(m * (1.0f / 32.0f));
#pragma unroll
            for (int bb = 0; bb < NB; ++bb) {
                bool h = (bin == bb);
                cnt[bb] += h ? 1.0f : 0.0f;
                sr[bb]  += h ? r : 0.0f;
                sg[bb]  += h ? g : 0.0f;
                sb[bb]  += h ? b : 0.0f;
            }
        }
    }

    // argmax over bins, first-max wins (strict >, ascending) — matches jnp.argmax
    float bc = cnt[0], br = sr[0], bg = sg[0], bbv = sb[0];
#pragma unroll
    for (int bb = 1; bb < NB; ++bb) {
        bool t = cnt[bb] > bc;
        bc  = t ? cnt[bb] : bc;
        br  = t ? sr[bb]  : br;
        bg  = t ? sg[bb]  : bg;
        bbv = t ? sb[bb]  : bbv;
    }

    float orv = br / bc;
    float ogv = bg / bc;
    float obv = bbv / bc;

    // write 8x8 block per channel, float4-vectorized (32B-aligned: ox*8 floats)
    size_t base = (size_t)(oy * PS) * W + (size_t)ox * PS;
    float vals[3] = { orv, ogv, obv };
#pragma unroll
    for (int c = 0; c < 3; ++c) {
        float v = vals[c];
        float4 vv = make_float4(v, v, v, v);
        float* oc = out + (size_t)c * H * W + base;
#pragma unroll
        for (int ry = 0; ry < PS; ++ry) {
            float4* p = (float4*)(oc + (size_t)ry * W);
            p[0] = vv;
            p[1] = vv;
        }
    }
}

extern "C" void kernel_launch(void* const* d_in, const int* in_sizes, int n_in,
                              void* d_out, int out_size, void* d_ws, size_t ws_size,
                              hipStream_t stream) {
    const float* rgb = (const float*)d_in[0];
    float* out = (float*)d_out;
    // params are fixed by setup_inputs(): num_bins=8, kernel_size=11, pixel_size=8
    int total = OH * OW;
    int block = 256;
    int grid = (total + block - 1) / block;
    hipLaunchKernelGGL(pixel_effect_kernel, dim3(grid), dim3(block), 0, stream, rgb, out);
}